// Round 16
// baseline (290.205 us; speedup 1.0000x reference)
//
#include <hip/hip_runtime.h>
#include <stdint.h>
#include <stddef.h>

#define N_NODES 24
#define MAX_K   4
#define BATCH   16
#define NODE_ELEMS (BATCH*128*32*32)   /* 2097152 elems; bf16 -> 4 MB/slot */

typedef unsigned short bfr;            /* raw bf16 */

/* ---------------- numpy RandomState(42) emulation (host side) ---------------- */
namespace nprng {
struct MT { uint32_t key[624]; int pos; };
static void seed_mt(MT& s, uint32_t sd){
  for(int i=0;i<624;i++){ s.key[i]=sd; sd = 1812433253u*(sd^(sd>>30)) + (uint32_t)i + 1u; }
  s.pos = 624;
}
static void gen(MT& s){
  const uint32_t UP=0x80000000u, LOW=0x7fffffffu, MA=0x9908b0dfu;
  uint32_t y; int i;
  for(i=0;i<227;i++){ y=(s.key[i]&UP)|(s.key[i+1]&LOW); s.key[i]=s.key[i+397]^(y>>1)^((y&1u)?MA:0u); }
  for(;i<623;i++){ y=(s.key[i]&UP)|(s.key[i+1]&LOW); s.key[i]=s.key[i-227]^(y>>1)^((y&1u)?MA:0u); }
  y=(s.key[623]&UP)|(s.key[0]&LOW); s.key[623]=s.key[396]^(y>>1)^((y&1u)?MA:0u);
  s.pos=0;
}
static uint32_t next32(MT& s){
  if(s.pos>=624) gen(s);
  uint32_t y=s.key[s.pos++];
  y^=y>>11; y^=(y<<7)&0x9d2c5680u; y^=(y<<15)&0xefc60000u; y^=y>>18;
  return y;
}
static uint64_t next64(MT& s){ uint64_t hi=next32(s); uint64_t lo=next32(s); return (hi<<32)|lo; }
static uint64_t gen_mask(uint64_t r){ r|=r>>1;r|=r>>2;r|=r>>4;r|=r>>8;r|=r>>16;r|=r>>32; return r; }
static long long np_randint(MT& s, long long low, long long high){
  uint64_t rng = (uint64_t)(high - 1 - low);
  if(rng==0) return low;
  uint64_t mask = gen_mask(rng), v;
  if(rng <= 0xffffffffull){ do { v = (uint64_t)next32(s) & mask; } while(v > rng); }
  else                    { do { v = next64(s) & mask; } while(v > rng); }
  return low + (long long)v;
}
static uint64_t np_interval(MT& s, uint64_t mx){
  if(mx==0) return 0;
  uint64_t mask = gen_mask(mx), v;
  if(mx <= 0xffffffffull){ do { v = (uint64_t)next32(s) & mask; } while(v > mx); }
  else                   { do { v = next64(s) & mask; } while(v > mx); }
  return v;
}
} // namespace nprng

/* ---------------- descriptors ---------------- */
struct NodeDesc {
  const bfr* pred[MAX_K];
  bfr* outp;
  int k;
  int idx;
};
struct LevelDesc { NodeDesc nd[8]; };
struct PtrList { const bfr* p[N_NODES]; int n; };

__device__ __forceinline__ float relu_(float v){ return v > 0.0f ? v : 0.0f; }
__device__ __forceinline__ float b2f(bfr h){ return __uint_as_float(((uint32_t)h) << 16); }
__device__ __forceinline__ bfr f2bf(float f){      /* round-to-nearest-even */
  uint32_t u = __float_as_uint(f);
  return (bfr)((u + 0x7fffu + ((u >> 16) & 1u)) >> 16);
}

/* XCD pinning (m09/T1): bid%8 -> XCD; image n lives on XCD n>>1 in every
   kernel. r9 level-sync structure (persistent scheduling refuted r12-r14).
   bf16 slots (r15) + bf16 ts tile: LDS 18.4KB -> 8 blocks/CU co-resident. */

/* ---------------- fused node kernel (nodes >= 1) ----------------
   512 threads, block = (img, row-pair) x node (y). grid (256, m<=8).
   phase A: thread = 2 ch x 4 px x BOTH rows; preds read as bf16x4 (8B);
            halo l/r via width-8 shuffles; ts stored bf16 (ushort4).
   phase B: wave = 16 couts (wave-uniform -> s_load weights); ds_read_u16
            + shift unpack; bf16 stores. */
__global__ __launch_bounds__(512, 8)
void k_node(LevelDesc L, const float* __restrict__ aggw, const float* __restrict__ dw,
            const float* __restrict__ pw, const float* __restrict__ gamma,
            const float* __restrict__ beta)
{
  const NodeDesc nd = L.nd[blockIdx.y];
  const int idx = nd.idx, k = nd.k;
  const int p = blockIdx.x & 7;
  const int q = blockIdx.x >> 3;          /* 0..31 */
  const int n = (p << 1) + (q >> 4);
  const int rp = q & 15;                  /* rows 2rp, 2rp+1 */
  const int tid = threadIdx.x;

  __shared__ __align__(16) bfr ts[2][128][36];   /* 18.4 KB */

  const float* agg = aggw + (idx << 2);
  const float w0 = 1.0f/(1.0f + __expf(-agg[0]));
  const float w1 = (k>1) ? 1.0f/(1.0f + __expf(-agg[1])) : 0.0f;
  const float w2 = (k>2) ? 1.0f/(1.0f + __expf(-agg[2])) : 0.0f;
  const float w3 = (k>3) ? 1.0f/(1.0f + __expf(-agg[3])) : 0.0f;
  const bfr* p0 = nd.pred[0];
  const bfr* p1 = nd.pred[1];
  const bfr* p2 = nd.pred[2];
  const bfr* p3 = nd.pred[3];
  const float* dwn = dw + (size_t)(idx - 1) * 1152;

  /* ---- phase A ---- */
  {
    const int rg = tid & 7, x4 = rg << 2;
    const int chg = tid >> 3;
    const int r0 = rp << 1;
#pragma unroll
    for(int cc = 0; cc < 2; ++cc){
      const int c = (chg << 1) + cc;
      const size_t bc = ((size_t)((n << 7) + c)) << 10;
      float dwv[9];
#pragma unroll
      for(int t = 0; t < 9; ++t) dwv[t] = dwn[t*128 + c];
      float a0=0.f,a1=0.f,a2=0.f,a3=0.f;     /* row r0   */
      float b0=0.f,b1=0.f,b2=0.f,b3=0.f;     /* row r0+1 */
#pragma unroll
      for(int j = 0; j < 4; ++j){
        const int iy = r0 - 1 + j;
        if((unsigned)iy < 32u){              /* block-uniform */
          const size_t off = bc + ((size_t)iy << 5) + x4;
          const ushort4 h0 = *(const ushort4*)(p0 + off);
          float mx = w0*b2f(h0.x), my = w0*b2f(h0.y);
          float mz = w0*b2f(h0.z), mw = w0*b2f(h0.w);
          if(k > 1){
            const ushort4 h = *(const ushort4*)(p1 + off);
            mx = fmaf(w1, b2f(h.x), mx); my = fmaf(w1, b2f(h.y), my);
            mz = fmaf(w1, b2f(h.z), mz); mw = fmaf(w1, b2f(h.w), mw);
          }
          if(k > 2){
            const ushort4 h = *(const ushort4*)(p2 + off);
            mx = fmaf(w2, b2f(h.x), mx); my = fmaf(w2, b2f(h.y), my);
            mz = fmaf(w2, b2f(h.z), mz); mw = fmaf(w2, b2f(h.w), mw);
          }
          if(k > 3){
            const ushort4 h = *(const ushort4*)(p3 + off);
            mx = fmaf(w3, b2f(h.x), mx); my = fmaf(w3, b2f(h.y), my);
            mz = fmaf(w3, b2f(h.z), mz); mw = fmaf(w3, b2f(h.w), mw);
          }
          /* halo from neighbor lanes (width-8 segment = this 32-px row) */
          float l = __shfl_up(mw, 1, 8);   if(rg == 0) l = 0.f;
          float r = __shfl_down(mx, 1, 8); if(rg == 7) r = 0.f;
          const float z0 = relu_(l),  z1 = relu_(mx), z2 = relu_(my);
          const float z3 = relu_(mz), z4 = relu_(mw), z5 = relu_(r);
          if(j < 3){
            const float d0 = dwv[j*3], d1 = dwv[j*3+1], d2 = dwv[j*3+2];
            a0 = fmaf(d0,z0, fmaf(d1,z1, fmaf(d2,z2, a0)));
            a1 = fmaf(d0,z1, fmaf(d1,z2, fmaf(d2,z3, a1)));
            a2 = fmaf(d0,z2, fmaf(d1,z3, fmaf(d2,z4, a2)));
            a3 = fmaf(d0,z3, fmaf(d1,z4, fmaf(d2,z5, a3)));
          }
          if(j > 0){
            const float d0 = dwv[(j-1)*3], d1 = dwv[(j-1)*3+1], d2 = dwv[(j-1)*3+2];
            b0 = fmaf(d0,z0, fmaf(d1,z1, fmaf(d2,z2, b0)));
            b1 = fmaf(d0,z1, fmaf(d1,z2, fmaf(d2,z3, b1)));
            b2 = fmaf(d0,z2, fmaf(d1,z3, fmaf(d2,z4, b2)));
            b3 = fmaf(d0,z3, fmaf(d1,z4, fmaf(d2,z5, b3)));
          }
        }
      }
      *(ushort4*)&ts[0][c][x4] = make_ushort4(f2bf(a0), f2bf(a1), f2bf(a2), f2bf(a3));
      *(ushort4*)&ts[1][c][x4] = make_ushort4(f2bf(b0), f2bf(b1), f2bf(b2), f2bf(b3));
    }
  }
  __syncthreads();

  /* ---- phase B: wave-uniform couts, scalar weight loads; bf16 LDS reads ---- */
  const int wv  = __builtin_amdgcn_readfirstlane(tid >> 6);   /* 0..7 */
  const int lane = tid & 63;
  const int ro = lane >> 5, px = lane & 31;
  const float* Wp  = pw + (size_t)(idx - 1) * 16384 + (wv << 4);
  const bfr* tsr = &ts[ro][0][px];
  float acc[16];
#pragma unroll
  for(int j = 0; j < 16; ++j) acc[j] = 0.f;
#pragma unroll 4
  for(int ci = 0; ci < 128; ++ci){
    const float tv = b2f(tsr[ci * 36]);        /* ds_read_u16, 2-way alias = free */
    const float* wr = Wp + (ci << 7);          /* wave-uniform -> s_load */
#pragma unroll
    for(int j = 0; j < 16; ++j) acc[j] = fmaf(wr[j], tv, acc[j]);
  }
  const int row = (rp << 1) + ro;
  const int cb = (idx << 7) + (wv << 4);
  bfr* op = nd.outp + (((size_t)((n << 7) + (wv << 4))) << 10) + (row << 5) + px;
#pragma unroll
  for(int j = 0; j < 16; ++j){
    const float gm = gamma[cb + j], bt = beta[cb + j];
    op[(size_t)j << 10] = f2bf(fmaf(acc[j], gm, bt));
  }
}

/* ---------------- fused node-0 kernel (stride-2, CIN=64, fp32 in / bf16 out) ---- */
__global__ __launch_bounds__(512, 8)
void k_node0(const float* __restrict__ x_in, const float* __restrict__ aggw,
             const float* __restrict__ dw0, const float* __restrict__ pw0,
             const float* __restrict__ gamma, const float* __restrict__ beta,
             bfr* __restrict__ outp)
{
  const int p = blockIdx.x & 7;
  const int q = blockIdx.x >> 3;
  const int n = (p << 1) + (q >> 4);
  const int rp = q & 15;
  const int tid = threadIdx.x;

  __shared__ __align__(16) bfr ts[2][64][36];    /* 9.2 KB */

  const float gate = 1.0f/(1.0f + __expf(-aggw[0]));

  /* ---- phase A: rg = tid&7 (4px), c = tid>>3, both rows; stride-2 ---- */
  {
    const int rg = tid & 7, x4 = rg << 2;
    const int c = tid >> 3;
    const int r0 = rp << 1;
    const size_t bc = ((size_t)((n << 6) + c)) << 12;
    float dwv[9];
#pragma unroll
    for(int t = 0; t < 9; ++t) dwv[t] = dw0[t*64 + c];
    float a0=0.f,a1=0.f,a2=0.f,a3=0.f;
    float b0=0.f,b1=0.f,b2=0.f,b3=0.f;
#pragma unroll
    for(int j = 0; j < 5; ++j){              /* input rows 2r0 .. 2r0+4 */
      const int iy = (r0 << 1) + j;
      if(iy < 64){                           /* block-uniform */
        const size_t off = bc + ((size_t)iy << 6) + (x4 << 1);
        const float4 va = *(const float4*)(x_in + off);
        const float4 vb = *(const float4*)(x_in + off + 4);
        float ve = __shfl_down(va.x, 1, 8);  /* next lane's first px */
        if(rg == 7) ve = 0.f;
        float z[9];
        z[0]=relu_(gate*va.x); z[1]=relu_(gate*va.y); z[2]=relu_(gate*va.z); z[3]=relu_(gate*va.w);
        z[4]=relu_(gate*vb.x); z[5]=relu_(gate*vb.y); z[6]=relu_(gate*vb.z); z[7]=relu_(gate*vb.w);
        z[8]=relu_(gate*ve);
        if(j < 3){
          const float d0 = dwv[j*3], d1 = dwv[j*3+1], d2 = dwv[j*3+2];
          a0 = fmaf(d0,z[0], fmaf(d1,z[1], fmaf(d2,z[2], a0)));
          a1 = fmaf(d0,z[2], fmaf(d1,z[3], fmaf(d2,z[4], a1)));
          a2 = fmaf(d0,z[4], fmaf(d1,z[5], fmaf(d2,z[6], a2)));
          a3 = fmaf(d0,z[6], fmaf(d1,z[7], fmaf(d2,z[8], a3)));
        }
        if(j >= 2){
          const float d0 = dwv[(j-2)*3], d1 = dwv[(j-2)*3+1], d2 = dwv[(j-2)*3+2];
          b0 = fmaf(d0,z[0], fmaf(d1,z[1], fmaf(d2,z[2], b0)));
          b1 = fmaf(d0,z[2], fmaf(d1,z[3], fmaf(d2,z[4], b1)));
          b2 = fmaf(d0,z[4], fmaf(d1,z[5], fmaf(d2,z[6], b2)));
          b3 = fmaf(d0,z[6], fmaf(d1,z[7], fmaf(d2,z[8], b3)));
        }
      }
    }
    *(ushort4*)&ts[0][c][x4] = make_ushort4(f2bf(a0), f2bf(a1), f2bf(a2), f2bf(a3));
    *(ushort4*)&ts[1][c][x4] = make_ushort4(f2bf(b0), f2bf(b1), f2bf(b2), f2bf(b3));
  }
  __syncthreads();

  /* ---- phase B: 64 ci -> 128 co; wave-uniform couts, scalar weights ---- */
  const int wv  = __builtin_amdgcn_readfirstlane(tid >> 6);
  const int lane = tid & 63;
  const int ro = lane >> 5, px = lane & 31;
  const float* Wp  = pw0 + (wv << 4);
  const bfr* tsr = &ts[ro][0][px];
  float acc[16];
#pragma unroll
  for(int j = 0; j < 16; ++j) acc[j] = 0.f;
#pragma unroll 4
  for(int ci = 0; ci < 64; ++ci){
    const float tv = b2f(tsr[ci * 36]);
    const float* wr = Wp + (ci << 7);
#pragma unroll
    for(int j = 0; j < 16; ++j) acc[j] = fmaf(wr[j], tv, acc[j]);
  }
  const int row = (rp << 1) + ro;
  bfr* op = outp + (((size_t)((n << 7) + (wv << 4))) << 10) + (row << 5) + px;
#pragma unroll
  for(int j = 0; j < 16; ++j){
    const float gm = gamma[(wv << 4) + j], bt = beta[(wv << 4) + j];
    op[(size_t)j << 10] = f2bf(fmaf(acc[j], gm, bt));
  }
}

/* ---------------- final mean over sinks (bf16 in, fp32 out, XCD-pinned) ---- */
__global__ __launch_bounds__(256)
void k_mean4(PtrList pl, float scale, float4* __restrict__ out)
{
  const int p = blockIdx.x & 7;
  const int q = blockIdx.x >> 3;          /* 0..255 */
  const int n = (p << 1) + (q >> 7);
  const int j = q & 127;
  const int i4 = n*32768 + j*256 + threadIdx.x;
  float4 s = make_float4(0.f,0.f,0.f,0.f);
  for(int t = 0; t < pl.n; ++t){
    const ushort4 h = ((const ushort4*)pl.p[t])[i4];
    s.x += b2f(h.x); s.y += b2f(h.y); s.z += b2f(h.z); s.w += b2f(h.w);
  }
  s.x *= scale; s.y *= scale; s.z *= scale; s.w *= scale;
  out[i4] = s;
}

/* ---------------- host ---------------- */
extern "C" void kernel_launch(void* const* d_in, const int* in_sizes, int n_in,
                              void* d_out, int out_size, void* d_ws, size_t ws_size,
                              hipStream_t stream)
{
  const float* x     = (const float*)d_in[0];
  const float* aggw  = (const float*)d_in[1];
  const float* dw0   = (const float*)d_in[2];
  const float* pw0   = (const float*)d_in[3];
  const float* dw    = (const float*)d_in[4];
  const float* pw    = (const float*)d_in[5];
  const float* gamma = (const float*)d_in[6];
  const float* beta  = (const float*)d_in[7];
  float* out = (float*)d_out;

  /* rebuild the reference's static DAG: np.random.RandomState(42) */
  int preds[N_NODES][MAX_K]; int npred[N_NODES];
  {
    nprng::MT st; nprng::seed_mt(st, 42u);
    npred[0] = 0;
    for(int i = 1; i < N_NODES; ++i){
      int mx = (i < MAX_K) ? i : MAX_K;
      int k = (int)nprng::np_randint(st, 1, (long long)mx + 1);
      int perm[N_NODES];
      for(int q = 0; q < i; ++q) perm[q] = q;
      for(int q = i-1; q >= 1; --q){
        int j = (int)nprng::np_interval(st, (uint64_t)q);
        int tt = perm[q]; perm[q] = perm[j]; perm[j] = tt;
      }
      int tmp[MAX_K];
      for(int a = 0; a < k; ++a) tmp[a] = perm[a];
      for(int a = 1; a < k; ++a){ int v = tmp[a]; int b = a-1;
        while(b >= 0 && tmp[b] > v){ tmp[b+1] = tmp[b]; --b; } tmp[b+1] = v; }
      npred[i] = k;
      for(int a = 0; a < k; ++a) preds[i][a] = tmp[a];
    }
  }

  /* sinks + topological levels */
  int uses[N_NODES]; bool sink[N_NODES];
  for(int i = 0; i < N_NODES; ++i) uses[i] = 0;
  for(int i = 0; i < N_NODES; ++i) for(int q = 0; q < npred[i]; ++q) uses[preds[i][q]]++;
  for(int i = 0; i < N_NODES; ++i) sink[i] = (uses[i] == 0);

  int level[N_NODES]; int maxlev = 0;
  level[0] = 0;
  for(int i = 1; i < N_NODES; ++i){
    int L = 0;
    for(int q = 0; q < npred[i]; ++q){ int l = level[preds[i][q]] + 1; if(l > L) L = l; }
    level[i] = L; if(L > maxlev) maxlev = L;
  }

  /* liveness slot allocation in level order; frees at level boundaries */
  int rem[N_NODES];
  for(int i = 0; i < N_NODES; ++i) rem[i] = uses[i] + (sink[i] ? 1 : 0);
  int slot_of[N_NODES]; bool slot_used[N_NODES]; int nslots = 0;
  for(int i = 0; i < N_NODES; ++i) slot_used[i] = false;
  for(int L = 0; L <= maxlev; ++L){
    for(int i = 0; i < N_NODES; ++i){
      if(level[i] != L) continue;
      int s = -1;
      for(int q = 0; q < nslots; ++q) if(!slot_used[q]){ s = q; break; }
      if(s < 0) s = nslots++;
      slot_used[s] = true; slot_of[i] = s;
    }
    for(int i = 0; i < N_NODES; ++i){
      if(level[i] != L) continue;
      for(int q = 0; q < npred[i]; ++q){
        int p = preds[i][q];
        if(--rem[p] == 0) slot_used[slot_of[p]] = false;
      }
    }
  }

  bfr* slotbase = (bfr*)d_ws;
  if(ws_size < (size_t)nslots * NODE_ELEMS * sizeof(bfr)) return;

  /* node descriptors */
  NodeDesc nds[N_NODES];
  for(int i = 0; i < N_NODES; ++i){
    nds[i].k = npred[i]; nds[i].idx = i;
    nds[i].outp = slotbase + (size_t)slot_of[i]*NODE_ELEMS;
    for(int q = 0; q < MAX_K; ++q){
      int src = (i == 0) ? 0 : preds[i][(q < npred[i]) ? q : 0];
      nds[i].pred[q] = slotbase + (size_t)slot_of[src]*NODE_ELEMS;
    }
  }

  /* level 0: node 0 */
  k_node0<<<dim3(256), dim3(512), 0, stream>>>(x, aggw, dw0, pw0, gamma, beta,
        nds[0].outp);

  /* levels 1..maxlev: full level per dispatch (chunks of 8) */
  for(int L = 1; L <= maxlev; ++L){
    int ids[N_NODES]; int cnt = 0;
    for(int i = 0; i < N_NODES; ++i) if(level[i] == L) ids[cnt++] = i;
    for(int off = 0; off < cnt; off += 8){
      int m = (cnt - off < 8) ? (cnt - off) : 8;
      LevelDesc ld;
      for(int j = 0; j < m; ++j) ld.nd[j] = nds[ids[off + j]];
      k_node<<<dim3(256, m), dim3(512), 0, stream>>>(ld, aggw, dw, pw, gamma, beta);
    }
  }

  /* final mean over sinks */
  PtrList pl; pl.n = 0;
  for(int i = 0; i < N_NODES; ++i) if(sink[i]) pl.p[pl.n++] = nds[i].outp;
  k_mean4<<<dim3(2048), dim3(256), 0, stream>>>(pl, 1.0f/(float)pl.n, (float4*)out);
}

// Round 18
// 262.276 us; speedup vs baseline: 1.1065x; 1.1065x over previous
//
#include <hip/hip_runtime.h>
#include <stdint.h>
#include <stddef.h>

#define N_NODES 24
#define MAX_K   4
#define BATCH   16
#define NODE_ELEMS (BATCH*128*32*32)   /* 2097152 elems; bf16 -> 4 MB/slot */

typedef unsigned short bfr;            /* raw bf16 */

/* ---------------- numpy RandomState(42) emulation (host side) ---------------- */
namespace nprng {
struct MT { uint32_t key[624]; int pos; };
static void seed_mt(MT& s, uint32_t sd){
  for(int i=0;i<624;i++){ s.key[i]=sd; sd = 1812433253u*(sd^(sd>>30)) + (uint32_t)i + 1u; }
  s.pos = 624;
}
static void gen(MT& s){
  const uint32_t UP=0x80000000u, LOW=0x7fffffffu, MA=0x9908b0dfu;
  uint32_t y; int i;
  for(i=0;i<227;i++){ y=(s.key[i]&UP)|(s.key[i+1]&LOW); s.key[i]=s.key[i+397]^(y>>1)^((y&1u)?MA:0u); }
  for(;i<623;i++){ y=(s.key[i]&UP)|(s.key[i+1]&LOW); s.key[i]=s.key[i-227]^(y>>1)^((y&1u)?MA:0u); }
  y=(s.key[623]&UP)|(s.key[0]&LOW); s.key[623]=s.key[396]^(y>>1)^((y&1u)?MA:0u);
  s.pos=0;
}
static uint32_t next32(MT& s){
  if(s.pos>=624) gen(s);
  uint32_t y=s.key[s.pos++];
  y^=y>>11; y^=(y<<7)&0x9d2c5680u; y^=(y<<15)&0xefc60000u; y^=y>>18;
  return y;
}
static uint64_t next64(MT& s){ uint64_t hi=next32(s); uint64_t lo=next32(s); return (hi<<32)|lo; }
static uint64_t gen_mask(uint64_t r){ r|=r>>1;r|=r>>2;r|=r>>4;r|=r>>8;r|=r>>16;r|=r>>32; return r; }
static long long np_randint(MT& s, long long low, long long high){
  uint64_t rng = (uint64_t)(high - 1 - low);
  if(rng==0) return low;
  uint64_t mask = gen_mask(rng), v;
  if(rng <= 0xffffffffull){ do { v = (uint64_t)next32(s) & mask; } while(v > rng); }
  else                    { do { v = next64(s) & mask; } while(v > rng); }
  return low + (long long)v;
}
static uint64_t np_interval(MT& s, uint64_t mx){
  if(mx==0) return 0;
  uint64_t mask = gen_mask(mx), v;
  if(mx <= 0xffffffffull){ do { v = (uint64_t)next32(s) & mask; } while(v > mx); }
  else                   { do { v = next64(s) & mask; } while(v > mx); }
  return v;
}
} // namespace nprng

/* ---------------- descriptors ---------------- */
struct NodeDesc {
  const bfr* pred[MAX_K];
  bfr* outp;
  int k;
  int idx;
};
struct LevelDesc { NodeDesc nd[8]; };
struct PtrList { const bfr* p[N_NODES]; int n; };

__device__ __forceinline__ float relu_(float v){ return v > 0.0f ? v : 0.0f; }
__device__ __forceinline__ float b2f(bfr h){ return __uint_as_float(((uint32_t)h) << 16); }
__device__ __forceinline__ float u2lo(uint32_t u){ return __uint_as_float(u << 16); }
__device__ __forceinline__ float u2hi(uint32_t u){ return __uint_as_float(u & 0xffff0000u); }
__device__ __forceinline__ bfr f2bf(float f){      /* round-to-nearest-even */
  uint32_t u = __float_as_uint(f);
  return (bfr)((u + 0x7fffu + ((u >> 16) & 1u)) >> 16);
}

/* XCD pinning (m09/T1): bid%8 -> XCD; image n lives on XCD n>>1 in every
   kernel. r9 level-sync structure (persistent scheduling refuted r12-r14;
   bf16-LDS occupancy r16 and packed-fma r17 both reverted). bf16 slots. */

/* ---------------- fused node kernel (nodes >= 1) ----------------
   512 threads, block = (img, row-pair) x node (y). grid (256, m<=8).
   phase A: thread = 2 ch x 4 px x BOTH rows; preds read as bf16x4 (8B);
            halo l/r via width-8 shuffles; ts fp32.
   phase B: wave = 16 couts (wave-uniform -> s_load weights); bf16 stores. */
__global__ __launch_bounds__(512, 4)
void k_node(LevelDesc L, const float* __restrict__ aggw, const float* __restrict__ dw,
            const float* __restrict__ pw, const float* __restrict__ gamma,
            const float* __restrict__ beta)
{
  const NodeDesc nd = L.nd[blockIdx.y];
  const int idx = nd.idx, k = nd.k;
  const int p = blockIdx.x & 7;
  const int q = blockIdx.x >> 3;          /* 0..31 */
  const int n = (p << 1) + (q >> 4);
  const int rp = q & 15;                  /* rows 2rp, 2rp+1 */
  const int tid = threadIdx.x;

  __shared__ __align__(16) float ts[2][128][36];   /* 36.9 KB */

  const float* agg = aggw + (idx << 2);
  const float w0 = 1.0f/(1.0f + __expf(-agg[0]));
  const float w1 = (k>1) ? 1.0f/(1.0f + __expf(-agg[1])) : 0.0f;
  const float w2 = (k>2) ? 1.0f/(1.0f + __expf(-agg[2])) : 0.0f;
  const float w3 = (k>3) ? 1.0f/(1.0f + __expf(-agg[3])) : 0.0f;
  const bfr* p0 = nd.pred[0];
  const bfr* p1 = nd.pred[1];
  const bfr* p2 = nd.pred[2];
  const bfr* p3 = nd.pred[3];
  const float* dwn = dw + (size_t)(idx - 1) * 1152;

  /* ---- phase A ---- */
  {
    const int rg = tid & 7, x4 = rg << 2;
    const int chg = tid >> 3;
    const int r0 = rp << 1;
#pragma unroll
    for(int cc = 0; cc < 2; ++cc){
      const int c = (chg << 1) + cc;
      const size_t bc = ((size_t)((n << 7) + c)) << 10;
      float dwv[9];
#pragma unroll
      for(int t = 0; t < 9; ++t) dwv[t] = dwn[t*128 + c];
      float a0=0.f,a1=0.f,a2=0.f,a3=0.f;     /* row r0   */
      float b0=0.f,b1=0.f,b2=0.f,b3=0.f;     /* row r0+1 */
#pragma unroll
      for(int j = 0; j < 4; ++j){
        const int iy = r0 - 1 + j;
        if((unsigned)iy < 32u){              /* block-uniform */
          const size_t off = bc + ((size_t)iy << 5) + x4;
          const ushort4 h0 = *(const ushort4*)(p0 + off);
          float mx = w0*b2f(h0.x), my = w0*b2f(h0.y);
          float mz = w0*b2f(h0.z), mw = w0*b2f(h0.w);
          if(k > 1){
            const ushort4 h = *(const ushort4*)(p1 + off);
            mx = fmaf(w1, b2f(h.x), mx); my = fmaf(w1, b2f(h.y), my);
            mz = fmaf(w1, b2f(h.z), mz); mw = fmaf(w1, b2f(h.w), mw);
          }
          if(k > 2){
            const ushort4 h = *(const ushort4*)(p2 + off);
            mx = fmaf(w2, b2f(h.x), mx); my = fmaf(w2, b2f(h.y), my);
            mz = fmaf(w2, b2f(h.z), mz); mw = fmaf(w2, b2f(h.w), mw);
          }
          if(k > 3){
            const ushort4 h = *(const ushort4*)(p3 + off);
            mx = fmaf(w3, b2f(h.x), mx); my = fmaf(w3, b2f(h.y), my);
            mz = fmaf(w3, b2f(h.z), mz); mw = fmaf(w3, b2f(h.w), mw);
          }
          /* halo from neighbor lanes (width-8 segment = this 32-px row) */
          float l = __shfl_up(mw, 1, 8);   if(rg == 0) l = 0.f;
          float r = __shfl_down(mx, 1, 8); if(rg == 7) r = 0.f;
          const float z0 = relu_(l),  z1 = relu_(mx), z2 = relu_(my);
          const float z3 = relu_(mz), z4 = relu_(mw), z5 = relu_(r);
          if(j < 3){
            const float d0 = dwv[j*3], d1 = dwv[j*3+1], d2 = dwv[j*3+2];
            a0 = fmaf(d0,z0, fmaf(d1,z1, fmaf(d2,z2, a0)));
            a1 = fmaf(d0,z1, fmaf(d1,z2, fmaf(d2,z3, a1)));
            a2 = fmaf(d0,z2, fmaf(d1,z3, fmaf(d2,z4, a2)));
            a3 = fmaf(d0,z3, fmaf(d1,z4, fmaf(d2,z5, a3)));
          }
          if(j > 0){
            const float d0 = dwv[(j-1)*3], d1 = dwv[(j-1)*3+1], d2 = dwv[(j-1)*3+2];
            b0 = fmaf(d0,z0, fmaf(d1,z1, fmaf(d2,z2, b0)));
            b1 = fmaf(d0,z1, fmaf(d1,z2, fmaf(d2,z3, b1)));
            b2 = fmaf(d0,z2, fmaf(d1,z3, fmaf(d2,z4, b2)));
            b3 = fmaf(d0,z3, fmaf(d1,z4, fmaf(d2,z5, b3)));
          }
        }
      }
      *(float4*)&ts[0][c][x4] = make_float4(a0,a1,a2,a3);
      *(float4*)&ts[1][c][x4] = make_float4(b0,b1,b2,b3);
    }
  }
  __syncthreads();

  /* ---- phase B: wave-uniform couts, scalar weight loads; bf16 store ---- */
  const int wv  = __builtin_amdgcn_readfirstlane(tid >> 6);   /* 0..7 */
  const int lane = tid & 63;
  const int ro = lane >> 5, px = lane & 31;
  const float* Wp  = pw + (size_t)(idx - 1) * 16384 + (wv << 4);
  const float* tsr = &ts[ro][0][px];
  float acc[16];
#pragma unroll
  for(int j = 0; j < 16; ++j) acc[j] = 0.f;
#pragma unroll 4
  for(int ci = 0; ci < 128; ++ci){
    const float tv = tsr[ci * 36];             /* ds_read_b32, 2-way alias = free */
    const float* wr = Wp + (ci << 7);          /* wave-uniform -> s_load */
#pragma unroll
    for(int j = 0; j < 16; ++j) acc[j] = fmaf(wr[j], tv, acc[j]);
  }
  const int row = (rp << 1) + ro;
  const int cb = (idx << 7) + (wv << 4);
  bfr* op = nd.outp + (((size_t)((n << 7) + (wv << 4))) << 10) + (row << 5) + px;
#pragma unroll
  for(int j = 0; j < 16; ++j){
    const float gm = gamma[cb + j], bt = beta[cb + j];
    op[(size_t)j << 10] = f2bf(fmaf(acc[j], gm, bt));
  }
}

/* ---------------- fused node-0 kernel (stride-2, CIN=64, fp32 in / bf16 out) ---- */
__global__ __launch_bounds__(512, 4)
void k_node0(const float* __restrict__ x_in, const float* __restrict__ aggw,
             const float* __restrict__ dw0, const float* __restrict__ pw0,
             const float* __restrict__ gamma, const float* __restrict__ beta,
             bfr* __restrict__ outp)
{
  const int p = blockIdx.x & 7;
  const int q = blockIdx.x >> 3;
  const int n = (p << 1) + (q >> 4);
  const int rp = q & 15;
  const int tid = threadIdx.x;

  __shared__ __align__(16) float ts[2][64][36];    /* 18.4 KB */

  const float gate = 1.0f/(1.0f + __expf(-aggw[0]));

  /* ---- phase A: rg = tid&7 (4px), c = tid>>3, both rows; stride-2 ---- */
  {
    const int rg = tid & 7, x4 = rg << 2;
    const int c = tid >> 3;
    const int r0 = rp << 1;
    const size_t bc = ((size_t)((n << 6) + c)) << 12;
    float dwv[9];
#pragma unroll
    for(int t = 0; t < 9; ++t) dwv[t] = dw0[t*64 + c];
    float a0=0.f,a1=0.f,a2=0.f,a3=0.f;
    float b0=0.f,b1=0.f,b2=0.f,b3=0.f;
#pragma unroll
    for(int j = 0; j < 5; ++j){              /* input rows 2r0 .. 2r0+4 */
      const int iy = (r0 << 1) + j;
      if(iy < 64){                           /* block-uniform */
        const size_t off = bc + ((size_t)iy << 6) + (x4 << 1);
        const float4 va = *(const float4*)(x_in + off);
        const float4 vb = *(const float4*)(x_in + off + 4);
        float ve = __shfl_down(va.x, 1, 8);  /* next lane's first px */
        if(rg == 7) ve = 0.f;
        float z[9];
        z[0]=relu_(gate*va.x); z[1]=relu_(gate*va.y); z[2]=relu_(gate*va.z); z[3]=relu_(gate*va.w);
        z[4]=relu_(gate*vb.x); z[5]=relu_(gate*vb.y); z[6]=relu_(gate*vb.z); z[7]=relu_(gate*vb.w);
        z[8]=relu_(gate*ve);
        if(j < 3){
          const float d0 = dwv[j*3], d1 = dwv[j*3+1], d2 = dwv[j*3+2];
          a0 = fmaf(d0,z[0], fmaf(d1,z[1], fmaf(d2,z[2], a0)));
          a1 = fmaf(d0,z[2], fmaf(d1,z[3], fmaf(d2,z[4], a1)));
          a2 = fmaf(d0,z[4], fmaf(d1,z[5], fmaf(d2,z[6], a2)));
          a3 = fmaf(d0,z[6], fmaf(d1,z[7], fmaf(d2,z[8], a3)));
        }
        if(j >= 2){
          const float d0 = dwv[(j-2)*3], d1 = dwv[(j-2)*3+1], d2 = dwv[(j-2)*3+2];
          b0 = fmaf(d0,z[0], fmaf(d1,z[1], fmaf(d2,z[2], b0)));
          b1 = fmaf(d0,z[2], fmaf(d1,z[3], fmaf(d2,z[4], b1)));
          b2 = fmaf(d0,z[4], fmaf(d1,z[5], fmaf(d2,z[6], b2)));
          b3 = fmaf(d0,z[6], fmaf(d1,z[7], fmaf(d2,z[8], b3)));
        }
      }
    }
    *(float4*)&ts[0][c][x4] = make_float4(a0,a1,a2,a3);
    *(float4*)&ts[1][c][x4] = make_float4(b0,b1,b2,b3);
  }
  __syncthreads();

  /* ---- phase B: 64 ci -> 128 co; wave-uniform couts, scalar weights ---- */
  const int wv  = __builtin_amdgcn_readfirstlane(tid >> 6);
  const int lane = tid & 63;
  const int ro = lane >> 5, px = lane & 31;
  const float* Wp  = pw0 + (wv << 4);
  const float* tsr = &ts[ro][0][px];
  float acc[16];
#pragma unroll
  for(int j = 0; j < 16; ++j) acc[j] = 0.f;
#pragma unroll 4
  for(int ci = 0; ci < 64; ++ci){
    const float tv = tsr[ci * 36];
    const float* wr = Wp + (ci << 7);
#pragma unroll
    for(int j = 0; j < 16; ++j) acc[j] = fmaf(wr[j], tv, acc[j]);
  }
  const int row = (rp << 1) + ro;
  bfr* op = outp + (((size_t)((n << 7) + (wv << 4))) << 10) + (row << 5) + px;
#pragma unroll
  for(int j = 0; j < 16; ++j){
    const float gm = gamma[(wv << 4) + j], bt = beta[(wv << 4) + j];
    op[(size_t)j << 10] = f2bf(fmaf(acc[j], gm, bt));
  }
}

/* ---------------- final mean over sinks (bf16x8 loads, fp32 out, XCD-pinned) ---- */
__global__ __launch_bounds__(256)
void k_mean8(PtrList pl, float scale, float4* __restrict__ out)
{
  const int p = blockIdx.x & 7;
  const int q = blockIdx.x >> 3;          /* 0..127 */
  const int n = (p << 1) + (q >> 6);
  const int j = q & 63;
  const int i8 = (n << 14) + (j << 8) + threadIdx.x;   /* 16384 8-elem groups/img */
  float s[8];
#pragma unroll
  for(int t = 0; t < 8; ++t) s[t] = 0.f;
  for(int t = 0; t < pl.n; ++t){
    const uint4 h = ((const uint4*)pl.p[t])[i8];       /* 8 bf16 = 16B */
    s[0] += u2lo(h.x); s[1] += u2hi(h.x);
    s[2] += u2lo(h.y); s[3] += u2hi(h.y);
    s[4] += u2lo(h.z); s[5] += u2hi(h.z);
    s[6] += u2lo(h.w); s[7] += u2hi(h.w);
  }
  const float4 o0 = make_float4(s[0]*scale, s[1]*scale, s[2]*scale, s[3]*scale);
  const float4 o1 = make_float4(s[4]*scale, s[5]*scale, s[6]*scale, s[7]*scale);
  out[(size_t)i8 * 2]     = o0;
  out[(size_t)i8 * 2 + 1] = o1;
}

/* ---------------- host ---------------- */
extern "C" void kernel_launch(void* const* d_in, const int* in_sizes, int n_in,
                              void* d_out, int out_size, void* d_ws, size_t ws_size,
                              hipStream_t stream)
{
  const float* x     = (const float*)d_in[0];
  const float* aggw  = (const float*)d_in[1];
  const float* dw0   = (const float*)d_in[2];
  const float* pw0   = (const float*)d_in[3];
  const float* dw    = (const float*)d_in[4];
  const float* pw    = (const float*)d_in[5];
  const float* gamma = (const float*)d_in[6];
  const float* beta  = (const float*)d_in[7];
  float* out = (float*)d_out;

  /* rebuild the reference's static DAG: np.random.RandomState(42) */
  int preds[N_NODES][MAX_K]; int npred[N_NODES];
  {
    nprng::MT st; nprng::seed_mt(st, 42u);
    npred[0] = 0;
    for(int i = 1; i < N_NODES; ++i){
      int mx = (i < MAX_K) ? i : MAX_K;
      int k = (int)nprng::np_randint(st, 1, (long long)mx + 1);
      int perm[N_NODES];
      for(int q = 0; q < i; ++q) perm[q] = q;
      for(int q = i-1; q >= 1; --q){
        int j = (int)nprng::np_interval(st, (uint64_t)q);
        int tt = perm[q]; perm[q] = perm[j]; perm[j] = tt;
      }
      int tmp[MAX_K];
      for(int a = 0; a < k; ++a) tmp[a] = perm[a];
      for(int a = 1; a < k; ++a){ int v = tmp[a]; int b = a-1;
        while(b >= 0 && tmp[b] > v){ tmp[b+1] = tmp[b]; --b; } tmp[b+1] = v; }
      npred[i] = k;
      for(int a = 0; a < k; ++a) preds[i][a] = tmp[a];
    }
  }

  /* sinks + topological levels */
  int uses[N_NODES]; bool sink[N_NODES];
  for(int i = 0; i < N_NODES; ++i) uses[i] = 0;
  for(int i = 0; i < N_NODES; ++i) for(int q = 0; q < npred[i]; ++q) uses[preds[i][q]]++;
  for(int i = 0; i < N_NODES; ++i) sink[i] = (uses[i] == 0);

  int level[N_NODES]; int maxlev = 0;
  level[0] = 0;
  for(int i = 1; i < N_NODES; ++i){
    int L = 0;
    for(int q = 0; q < npred[i]; ++q){ int l = level[preds[i][q]] + 1; if(l > L) L = l; }
    level[i] = L; if(L > maxlev) maxlev = L;
  }

  /* liveness slot allocation in level order; frees at level boundaries */
  int rem[N_NODES];
  for(int i = 0; i < N_NODES; ++i) rem[i] = uses[i] + (sink[i] ? 1 : 0);
  int slot_of[N_NODES]; bool slot_used[N_NODES]; int nslots = 0;
  for(int i = 0; i < N_NODES; ++i) slot_used[i] = false;
  for(int L = 0; L <= maxlev; ++L){
    for(int i = 0; i < N_NODES; ++i){
      if(level[i] != L) continue;
      int s = -1;
      for(int q = 0; q < nslots; ++q) if(!slot_used[q]){ s = q; break; }
      if(s < 0) s = nslots++;
      slot_used[s] = true; slot_of[i] = s;
    }
    for(int i = 0; i < N_NODES; ++i){
      if(level[i] != L) continue;
      for(int q = 0; q < npred[i]; ++q){
        int p = preds[i][q];
        if(--rem[p] == 0) slot_used[slot_of[p]] = false;
      }
    }
  }

  bfr* slotbase = (bfr*)d_ws;
  if(ws_size < (size_t)nslots * NODE_ELEMS * sizeof(bfr)) return;

  /* node descriptors */
  NodeDesc nds[N_NODES];
  for(int i = 0; i < N_NODES; ++i){
    nds[i].k = npred[i]; nds[i].idx = i;
    nds[i].outp = slotbase + (size_t)slot_of[i]*NODE_ELEMS;
    for(int q = 0; q < MAX_K; ++q){
      int src = (i == 0) ? 0 : preds[i][(q < npred[i]) ? q : 0];
      nds[i].pred[q] = slotbase + (size_t)slot_of[src]*NODE_ELEMS;
    }
  }

  /* level 0: node 0 */
  k_node0<<<dim3(256), dim3(512), 0, stream>>>(x, aggw, dw0, pw0, gamma, beta,
        nds[0].outp);

  /* levels 1..maxlev: full level per dispatch (chunks of 8) */
  for(int L = 1; L <= maxlev; ++L){
    int ids[N_NODES]; int cnt = 0;
    for(int i = 0; i < N_NODES; ++i) if(level[i] == L) ids[cnt++] = i;
    for(int off = 0; off < cnt; off += 8){
      int m = (cnt - off < 8) ? (cnt - off) : 8;
      LevelDesc ld;
      for(int j = 0; j < m; ++j) ld.nd[j] = nds[ids[off + j]];
      k_node<<<dim3(256, m), dim3(512), 0, stream>>>(ld, aggw, dw, pw, gamma, beta);
    }
  }

  /* final mean over sinks */
  PtrList pl; pl.n = 0;
  for(int i = 0; i < N_NODES; ++i) if(sink[i]) pl.p[pl.n++] = nds[i].outp;
  k_mean8<<<dim3(1024), dim3(256), 0, stream>>>(pl, 1.0f/(float)pl.n, (float4*)out);
}